// Round 8
// baseline (220.427 us; speedup 1.0000x reference)
//
#include <hip/hip_runtime.h>

#pragma clang fp contract(off)

typedef __attribute__((ext_vector_type(8))) short short8;
typedef __attribute__((ext_vector_type(4))) float f32x4;

#define MARGIN 0.02f

static __device__ __forceinline__ unsigned short f2b(float f) {
    union { float f; unsigned u; } x; x.f = f;
    unsigned u = x.u;
    return (unsigned short)((u + 0x7FFFu + ((u >> 16) & 1u)) >> 16);
}

// Bit-exact np distance: dot = single-accumulator ascending-k FMA chain on
// full-precision fp32 z; d = (zn - 2*dot) + en, each op single-rounded.
template <int ES>
static __device__ __forceinline__ float np_dist(
    const float* __restrict__ zr, const float* __restrict__ ecol,
    float zn, float en) {
    float c = 0.f;
    #pragma unroll
    for (int i = 0; i < 64; ++i) c = fmaf(zr[i], ecol[i * ES], c);
    float t = zn - 2.f * c;
    return t + en;
}

// ---------------------------------------------------------------------------
// Prep: Et transpose (optional) + exact enorm + zero loss/counter.
// 256 blocks x 256 threads.
// ---------------------------------------------------------------------------
__global__ __launch_bounds__(256) void vq_prep(
    const float* __restrict__ E, float* __restrict__ Et,
    float* __restrict__ ws_loss, unsigned* __restrict__ ws_cnt,
    float* __restrict__ enorm, int writeEt) {
    int t = blockIdx.x * 256 + threadIdx.x;  // 0..65535
    if (writeEt) Et[t] = E[(t & 63) * 1024 + (t >> 6)];
    if (t < 1024) {
        float s2 = 0.f;
        #pragma unroll
        for (int d = 0; d < 64; ++d) {
            float v = E[d * 1024 + t];
            s2 = fmaf(v, v, s2);
        }
        enorm[t] = s2;
    }
    if (t == 0) { *ws_loss = 0.f; *ws_cnt = 0u; }
}

// ---------------------------------------------------------------------------
// Main: MFMA screen with sortable-key top-2 (5 VALU/cand), ambiguity-gated
// bit-exact re-eval, gather, loss (+last-block final write).
// Block = 512 thr (8 waves), 256 rows/block, grid = 512. LDS ~39 KB.
// ---------------------------------------------------------------------------
template <bool USE_ET>
__global__ __launch_bounds__(512) void vq_main(
    const float* __restrict__ z, const float* __restrict__ E,
    const float* __restrict__ Et, const float* __restrict__ enorm,
    float* __restrict__ ws_loss, unsigned* __restrict__ ws_cnt,
    float* __restrict__ out) {
    __shared__ unsigned short sB[256 * 64];  // 32 KB swizzled bf16 B-tile
    __shared__ float sEn[1024];              // exact codebook norms
    __shared__ float sZn[256];               // exact |z|^2 per row
    __shared__ int sIdx[256];
    __shared__ float sRed[8];

    const int tid = threadIdx.x;
    const int w = tid >> 6;        // wave 0..7
    const int l = tid & 63;
    const int quad = l >> 4;
    const int m = l & 15;
    const int b = blockIdx.x;

    ((float2*)sEn)[tid] = ((const float2*)enorm)[tid];  // 512 x 2 = 1024

    // znorm: bit-exact numpy pairwise sum (SSE path, 4 accs, hadd), rows 0..255
    if (tid < 256) {
        const float* zr = z + (b * 256 + tid) * 64;
        float S[16];
        #pragma unroll
        for (int u = 0; u < 16; ++u) { float v = zr[u]; S[u] = v * v; }
        #pragma unroll
        for (int t = 1; t < 4; ++t)
            #pragma unroll
            for (int u = 0; u < 16; ++u) {
                float v = zr[16 * t + u];
                float sq = v * v;
                S[u] = S[u] + sq;
            }
        float R0 = (S[0] + S[4]) + (S[8] + S[12]);
        float R1 = (S[1] + S[5]) + (S[9] + S[13]);
        float R2 = (S[2] + S[6]) + (S[10] + S[14]);
        float R3 = (S[3] + S[7]) + (S[11] + S[15]);
        sZn[tid] = (R0 + R1) + (R2 + R3);
    }

    // A fragments (fp32 -> bf16 RNE, screening only)
    short8 a[2][2];
    #pragma unroll
    for (int rt = 0; rt < 2; ++rt) {
        const int rowl = w * 32 + rt * 16 + m;
        #pragma unroll
        for (int s = 0; s < 2; ++s) {
            const float* zp = z + (b * 256 + rowl) * 64 + s * 32 + quad * 8;
            union { float4 v; float f[4]; } u0, u1;
            u0.v = *(const float4*)zp;
            u1.v = *(const float4*)(zp + 4);
            short8 av;
            #pragma unroll
            for (int j = 0; j < 4; ++j) av[j] = (short)f2b(u0.f[j]);
            #pragma unroll
            for (int j = 0; j < 4; ++j) av[4 + j] = (short)f2b(u1.f[j]);
            a[rt][s] = av;
        }
    }

    // sortable-key top-2 per slot: key = (bits(en+16-2dot) & ~1023) | col
    unsigned k1[2][4], k2[2][4];
    #pragma unroll
    for (int rt = 0; rt < 2; ++rt)
        #pragma unroll
        for (int r = 0; r < 4; ++r) { k1[rt][r] = 0xFFFFFFFFu; k2[rt][r] = 0xFFFFFFFFu; }

    for (int h = 0; h < 4; ++h) {
        // stage 256 cols x 64 dims as bf16, XOR-swizzled 16B k-groups
        if (USE_ET) {
            #pragma unroll
            for (int i = 0; i < 8; ++i) {
                const int u = tid + i * 512;     // 0..4095
                const int col = u >> 4;          // 0..255
                const int dg = u & 15;           // d = dg*4
                union { float4 v; float f[4]; } vv;
                vv.v = *(const float4*)(Et + (h * 256 + col) * 64 + dg * 4);
                unsigned p0 = f2b(vv.f[0]) | (f2b(vv.f[1]) << 16);
                unsigned p1 = f2b(vv.f[2]) | (f2b(vv.f[3]) << 16);
                const int gi = col * 8 + ((dg >> 1) ^ (col & 7));
                uint2 pk; pk.x = p0; pk.y = p1;
                *(uint2*)&sB[gi * 8 + (dg & 1) * 4] = pk;
            }
        } else {
            #pragma unroll
            for (int i = 0; i < 4; ++i) {
                const int u = tid + i * 512;     // 0..2047
                const int d0 = (u & 31) * 2;
                const int cg = u >> 5;           // 0..63, 4 cols each
                const float* e0 = E + d0 * 1024 + h * 256 + cg * 4;
                union { float4 v; float f[4]; } va, vb;
                va.v = *(const float4*)e0;
                vb.v = *(const float4*)(e0 + 1024);
                #pragma unroll
                for (int j = 0; j < 4; ++j) {
                    const int col = cg * 4 + j;
                    unsigned pk = f2b(va.f[j]) | (f2b(vb.f[j]) << 16);
                    const int gi = col * 8 + ((d0 >> 3) ^ (col & 7));
                    *(unsigned*)&sB[gi * 8 + (d0 & 7)] = pk;
                }
            }
        }
        __syncthreads();

        #pragma unroll
        for (int ct = 0; ct < 16; ++ct) {
            const int cc = h * 16 + ct;          // global 16-col tile 0..63
            const int colb = (ct * 16 + m) * 8;
            short8 b0 = *(const short8*)&sB[(colb + (quad ^ (m & 7))) * 8];
            short8 b1 = *(const short8*)&sB[(colb + ((4 + quad) ^ (m & 7))) * 8];
            f32x4 acc0 = {0.f, 0.f, 0.f, 0.f};
            f32x4 acc1 = {0.f, 0.f, 0.f, 0.f};
            acc0 = __builtin_amdgcn_mfma_f32_16x16x32_bf16(a[0][0], b0, acc0, 0, 0, 0);
            acc0 = __builtin_amdgcn_mfma_f32_16x16x32_bf16(a[0][1], b1, acc0, 0, 0, 0);
            acc1 = __builtin_amdgcn_mfma_f32_16x16x32_bf16(a[1][0], b0, acc1, 0, 0, 0);
            acc1 = __builtin_amdgcn_mfma_f32_16x16x32_bf16(a[1][1], b1, acc1, 0, 0, 0);
            const float en16 = sEn[cc * 16 + m] + 16.f;
            const unsigned colk = (unsigned)(cc * 16 + m);
            #pragma unroll
            for (int r = 0; r < 4; ++r) {
                float v0 = fmaf(-2.f, acc0[r], en16);
                unsigned key0 = (__float_as_uint(v0) & 0xFFFFFC00u) | colk;
                k2[0][r] = min(max(key0, k1[0][r]), k2[0][r]);
                k1[0][r] = min(key0, k1[0][r]);
                float v1 = fmaf(-2.f, acc1[r], en16);
                unsigned key1 = (__float_as_uint(v1) & 0xFFFFFC00u) | colk;
                k2[1][r] = min(max(key1, k1[1][r]), k2[1][r]);
                k1[1][r] = min(key1, k1[1][r]);
            }
        }
        __syncthreads();
    }

    // per-slot: find best + global second; re-eval only if ambiguous
    float la = 0.f;
    #pragma unroll
    for (int rt = 0; rt < 2; ++rt) {
        #pragma unroll
        for (int r = 0; r < 4; ++r) {
            unsigned kb = k1[rt][r];
            #pragma unroll
            for (int mask = 1; mask <= 8; mask <<= 1)
                kb = min(kb, (unsigned)__shfl_xor((int)kb, mask));
            unsigned sec = (k1[rt][r] == kb) ? k2[rt][r] : k1[rt][r];
            #pragma unroll
            for (int mask = 1; mask <= 8; mask <<= 1)
                sec = min(sec, (unsigned)__shfl_xor((int)sec, mask));
            const float vkb = __uint_as_float(kb & 0xFFFFFC00u);
            const float vsec = __uint_as_float(sec & 0xFFFFFC00u);
            const int rowl = w * 32 + rt * 16 + quad * 4 + r;
            const float zn = sZn[rowl];
            if (vsec > vkb + MARGIN) {
                // unambiguous (13-sigma): screen winner is the np argmin
                if (m == 0) {
                    sIdx[rowl] = (int)(kb & 1023u);
                    la += zn + (vkb - 16.f);
                }
            } else {
                const float* zr = z + (b * 256 + rowl) * 64;
                float d = 3.4e38f;
                int kk = 0x7fffffff;
                if (__uint_as_float(k1[rt][r] & 0xFFFFFC00u) <= vkb + MARGIN) {
                    kk = (int)(k1[rt][r] & 1023u);
                    d = USE_ET ? np_dist<1>(zr, Et + kk * 64, zn, sEn[kk])
                               : np_dist<1024>(zr, E + kk, zn, sEn[kk]);
                }
                if (__uint_as_float(k2[rt][r] & 0xFFFFFC00u) <= vkb + MARGIN) {
                    int kc = (int)(k2[rt][r] & 1023u);
                    float dd = USE_ET ? np_dist<1>(zr, Et + kc * 64, zn, sEn[kc])
                                      : np_dist<1024>(zr, E + kc, zn, sEn[kc]);
                    if (dd < d || (dd == d && kc < kk)) { d = dd; kk = kc; }
                }
                #pragma unroll
                for (int mask = 1; mask <= 8; mask <<= 1) {
                    float d2 = __shfl_xor(d, mask);
                    int c2 = __shfl_xor(kk, mask);
                    bool take = (d2 < d) || (d2 == d && c2 < kk);
                    d = take ? d2 : d;
                    kk = take ? c2 : kk;
                }
                if (m == 0) {
                    sIdx[rowl] = kk;
                    la += d;
                }
            }
        }
    }

    // wave loss reduce
    #pragma unroll
    for (int mask = 32; mask >= 1; mask >>= 1) la += __shfl_xor(la, mask);
    if (l == 0) sRed[w] = la;
    __syncthreads();

    // gather: 2 lanes/row, 32 dims each
    {
        const int row_local = tid >> 1;   // 0..255
        const int half = tid & 1;
        const int idx = sIdx[row_local];
        union { float s[32]; float4 f[8]; } tmp;
        if (USE_ET) {
            const float4* src = (const float4*)(Et + idx * 64 + half * 32);
            #pragma unroll
            for (int q4 = 0; q4 < 8; ++q4) tmp.f[q4] = src[q4];
        } else {
            #pragma unroll
            for (int dd = 0; dd < 32; ++dd) tmp.s[dd] = E[(half * 32 + dd) * 1024 + idx];
        }
        float4* dst = (float4*)(out + (b * 256 + row_local) * 64 + half * 32);
        #pragma unroll
        for (int q4 = 0; q4 < 8; ++q4) dst[q4] = tmp.f[q4];
    }

    // block loss -> global; last block writes the scalar
    if (tid == 0) {
        float bl = 0.f;
        #pragma unroll
        for (int i = 0; i < 8; ++i) bl += sRed[i];
        atomicAdd(ws_loss, bl);
        __threadfence();
        unsigned prev = atomicAdd(ws_cnt, 1u);
        if (prev == 511u) {
            float total = atomicAdd(ws_loss, 0.f);
            out[8388608] = total * (1.25f / 8388608.f);
        }
    }
}

extern "C" void kernel_launch(void* const* d_in, const int* in_sizes, int n_in,
                              void* d_out, int out_size, void* d_ws, size_t ws_size,
                              hipStream_t stream) {
    const float* z = (const float*)d_in[0];  // fp32 [131072,64]
    const float* E = (const float*)d_in[1];  // fp32 [64,1024]
    float* out = (float*)d_out;              // fp32 [8388609]

    char* ws = (char*)d_ws;
    float* loss = (float*)ws;               // 4 B
    unsigned* cnt = (unsigned*)(ws + 64);   // 4 B
    float* enorm = (float*)(ws + 128);      // 4 KB
    float* Et = (float*)(ws + 8192);        // 256 KB (optional)
    const bool useEt = ws_size >= (size_t)(8192 + 65536 * 4);

    vq_prep<<<256, 256, 0, stream>>>(E, Et, loss, cnt, enorm, useEt ? 1 : 0);
    if (useEt)
        vq_main<true><<<512, 512, 0, stream>>>(z, E, Et, enorm, loss, cnt, out);
    else
        vq_main<false><<<512, 512, 0, stream>>>(z, E, Et, enorm, loss, cnt, out);
}

// Round 9
// 198.550 us; speedup vs baseline: 1.1102x; 1.1102x over previous
//
#include <hip/hip_runtime.h>

#pragma clang fp contract(off)

typedef __attribute__((ext_vector_type(8))) short short8;
typedef __attribute__((ext_vector_type(4))) float f32x4;

#define MARGIN 0.02f

static __device__ __forceinline__ unsigned short f2b(float f) {
    union { float f; unsigned u; } x; x.f = f;
    unsigned u = x.u;
    return (unsigned short)((u + 0x7FFFu + ((u >> 16) & 1u)) >> 16);
}

// Bit-exact np distance: dot = single-accumulator ascending-k FMA chain on
// full-precision fp32 z; d = (zn - 2*dot) + en, each op single-rounded.
template <int ES>
static __device__ __forceinline__ float np_dist(
    const float* __restrict__ zr, const float* __restrict__ ecol,
    float zn, float en) {
    float c = 0.f;
    #pragma unroll
    for (int i = 0; i < 64; ++i) c = fmaf(zr[i], ecol[i * ES], c);
    float t = zn - 2.f * c;
    return t + en;
}

// ---------------------------------------------------------------------------
// Prep: Et transpose (optional) + exact enorm + zero loss/counter.
// 256 blocks x 256 threads.
// ---------------------------------------------------------------------------
__global__ __launch_bounds__(256) void vq_prep(
    const float* __restrict__ E, float* __restrict__ Et,
    float* __restrict__ ws_loss, unsigned* __restrict__ ws_cnt,
    float* __restrict__ enorm, int writeEt) {
    int t = blockIdx.x * 256 + threadIdx.x;  // 0..65535
    if (writeEt) Et[t] = E[(t & 63) * 1024 + (t >> 6)];
    if (t < 1024) {
        float s2 = 0.f;
        #pragma unroll
        for (int d = 0; d < 64; ++d) {
            float v = E[d * 1024 + t];
            s2 = fmaf(v, v, s2);
        }
        enorm[t] = s2;
    }
    if (t == 0) { *ws_loss = 0.f; *ws_cnt = 0u; }
}

// ---------------------------------------------------------------------------
// Main: MFMA screen with sortable-key top-2, ambiguity-gated bit-exact
// re-eval, gather, loss (+last-block final write).
// Block = 256 thr (4 waves), 128 rows/block, grid = 1024. LDS ~21.5 KB.
// Geometry identical to round 7 (60 VGPRs, no spill).
// ---------------------------------------------------------------------------
template <bool USE_ET>
__global__ __launch_bounds__(256) void vq_main(
    const float* __restrict__ z, const float* __restrict__ E,
    const float* __restrict__ Et, const float* __restrict__ enorm,
    float* __restrict__ ws_loss, unsigned* __restrict__ ws_cnt,
    float* __restrict__ out) {
    __shared__ unsigned short sB[128 * 64];  // 16 KB swizzled bf16 B-tile
    __shared__ float sEn[1024];
    __shared__ float sZn[128];
    __shared__ int sIdx[128];
    __shared__ float sRed[4];

    const int tid = threadIdx.x;
    const int w = tid >> 6;
    const int l = tid & 63;
    const int quad = l >> 4;
    const int m = l & 15;
    const int b = blockIdx.x;

    ((float4*)sEn)[tid] = ((const float4*)enorm)[tid];

    // znorm: bit-exact numpy pairwise sum (SSE path, 4 accs, hadd)
    if (tid < 128) {
        const float* zr = z + (b * 128 + tid) * 64;
        float S[16];
        #pragma unroll
        for (int u = 0; u < 16; ++u) { float v = zr[u]; S[u] = v * v; }
        #pragma unroll
        for (int t = 1; t < 4; ++t)
            #pragma unroll
            for (int u = 0; u < 16; ++u) {
                float v = zr[16 * t + u];
                float sq = v * v;
                S[u] = S[u] + sq;
            }
        float R0 = (S[0] + S[4]) + (S[8] + S[12]);
        float R1 = (S[1] + S[5]) + (S[9] + S[13]);
        float R2 = (S[2] + S[6]) + (S[10] + S[14]);
        float R3 = (S[3] + S[7]) + (S[11] + S[15]);
        sZn[tid] = (R0 + R1) + (R2 + R3);
    }

    // A fragments (fp32 -> bf16 RNE, screening only)
    short8 a[2][2];
    #pragma unroll
    for (int rt = 0; rt < 2; ++rt) {
        const int rowl = w * 32 + rt * 16 + m;
        #pragma unroll
        for (int s = 0; s < 2; ++s) {
            const float* zp = z + (b * 128 + rowl) * 64 + s * 32 + quad * 8;
            union { float4 v; float f[4]; } u0, u1;
            u0.v = *(const float4*)zp;
            u1.v = *(const float4*)(zp + 4);
            short8 av;
            #pragma unroll
            for (int j = 0; j < 4; ++j) av[j] = (short)f2b(u0.f[j]);
            #pragma unroll
            for (int j = 0; j < 4; ++j) av[4 + j] = (short)f2b(u1.f[j]);
            a[rt][s] = av;
        }
    }

    // sortable-key top-2 per slot: key = (bits(en+16-2dot) & ~1023) | col
    unsigned k1[2][4], k2[2][4];
    #pragma unroll
    for (int rt = 0; rt < 2; ++rt)
        #pragma unroll
        for (int r = 0; r < 4; ++r) { k1[rt][r] = 0xFFFFFFFFu; k2[rt][r] = 0xFFFFFFFFu; }

    for (int st = 0; st < 8; ++st) {
        // stage 128 cols x 64 dims of E as bf16, XOR-swizzled 16B k-groups
        // (round-7 staging: modest unroll, no spill)
        #pragma unroll
        for (int i = 0; i < 4; ++i) {
            const int u = tid + i * 256;       // 0..1023
            const int d0 = (u & 31) * 2;
            const int cg = u >> 5;             // 0..31 (4 cols each)
            const float* e0 = E + d0 * 1024 + st * 128 + cg * 4;
            union { float4 v; float f[4]; } va, vb;
            va.v = *(const float4*)e0;
            vb.v = *(const float4*)(e0 + 1024);
            #pragma unroll
            for (int j = 0; j < 4; ++j) {
                const int col = cg * 4 + j;    // local col 0..127
                unsigned pk = f2b(va.f[j]) | (f2b(vb.f[j]) << 16);
                const int gi = col * 8 + ((d0 >> 3) ^ (col & 7));
                *(unsigned*)&sB[gi * 8 + (d0 & 7)] = pk;
            }
        }
        __syncthreads();

        #pragma unroll
        for (int ct = 0; ct < 8; ++ct) {
            const int cc = st * 8 + ct;        // global 16-col tile 0..63
            const int colb = (ct * 16 + m) * 8;
            short8 b0 = *(const short8*)&sB[(colb + (quad ^ (m & 7))) * 8];
            short8 b1 = *(const short8*)&sB[(colb + ((4 + quad) ^ (m & 7))) * 8];
            f32x4 acc0 = {0.f, 0.f, 0.f, 0.f};
            f32x4 acc1 = {0.f, 0.f, 0.f, 0.f};
            acc0 = __builtin_amdgcn_mfma_f32_16x16x32_bf16(a[0][0], b0, acc0, 0, 0, 0);
            acc0 = __builtin_amdgcn_mfma_f32_16x16x32_bf16(a[0][1], b1, acc0, 0, 0, 0);
            acc1 = __builtin_amdgcn_mfma_f32_16x16x32_bf16(a[1][0], b0, acc1, 0, 0, 0);
            acc1 = __builtin_amdgcn_mfma_f32_16x16x32_bf16(a[1][1], b1, acc1, 0, 0, 0);
            const float en16 = sEn[cc * 16 + m] + 16.f;
            const unsigned colk = (unsigned)(cc * 16 + m);
            #pragma unroll
            for (int r = 0; r < 4; ++r) {
                float v0 = fmaf(-2.f, acc0[r], en16);
                unsigned key0 = (__float_as_uint(v0) & 0xFFFFFC00u) | colk;
                k2[0][r] = min(max(key0, k1[0][r]), k2[0][r]);
                k1[0][r] = min(key0, k1[0][r]);
                float v1 = fmaf(-2.f, acc1[r], en16);
                unsigned key1 = (__float_as_uint(v1) & 0xFFFFFC00u) | colk;
                k2[1][r] = min(max(key1, k1[1][r]), k2[1][r]);
                k1[1][r] = min(key1, k1[1][r]);
            }
        }
        __syncthreads();
    }

    // per-slot: global best + global second; re-eval only if ambiguous
    float la = 0.f;
    #pragma unroll
    for (int rt = 0; rt < 2; ++rt) {
        #pragma unroll
        for (int r = 0; r < 4; ++r) {
            unsigned kb = k1[rt][r];
            #pragma unroll
            for (int mask = 1; mask <= 8; mask <<= 1)
                kb = min(kb, (unsigned)__shfl_xor((int)kb, mask));
            unsigned sec = (k1[rt][r] == kb) ? k2[rt][r] : k1[rt][r];
            #pragma unroll
            for (int mask = 1; mask <= 8; mask <<= 1)
                sec = min(sec, (unsigned)__shfl_xor((int)sec, mask));
            const float vkb = __uint_as_float(kb & 0xFFFFFC00u);
            const float vsec = __uint_as_float(sec & 0xFFFFFC00u);
            const int rowl = w * 32 + rt * 16 + quad * 4 + r;
            const float zn = sZn[rowl];
            if (vsec > vkb + MARGIN) {
                // unambiguous (>=13 sigma): screen winner is the np argmin
                if (m == 0) {
                    sIdx[rowl] = (int)(kb & 1023u);
                    la += zn + (vkb - 16.f);
                }
            } else {
                const float* zr = z + (b * 128 + rowl) * 64;
                float d = 3.4e38f;
                int kk = 0x7fffffff;
                if (__uint_as_float(k1[rt][r] & 0xFFFFFC00u) <= vkb + MARGIN) {
                    kk = (int)(k1[rt][r] & 1023u);
                    d = USE_ET ? np_dist<1>(zr, Et + kk * 64, zn, sEn[kk])
                               : np_dist<1024>(zr, E + kk, zn, sEn[kk]);
                }
                if (__uint_as_float(k2[rt][r] & 0xFFFFFC00u) <= vkb + MARGIN) {
                    int kc = (int)(k2[rt][r] & 1023u);
                    float dd = USE_ET ? np_dist<1>(zr, Et + kc * 64, zn, sEn[kc])
                                      : np_dist<1024>(zr, E + kc, zn, sEn[kc]);
                    if (dd < d || (dd == d && kc < kk)) { d = dd; kk = kc; }
                }
                #pragma unroll
                for (int mask = 1; mask <= 8; mask <<= 1) {
                    float d2 = __shfl_xor(d, mask);
                    int c2 = __shfl_xor(kk, mask);
                    bool take = (d2 < d) || (d2 == d && c2 < kk);
                    d = take ? d2 : d;
                    kk = take ? c2 : kk;
                }
                if (m == 0) {
                    sIdx[rowl] = kk;
                    la += d;
                }
            }
        }
    }
    __syncthreads();

    // gather: 2 lanes/row, 32 dims each (contiguous from Et when available)
    {
        const int row_local = w * 32 + (l >> 1);
        const int half = l & 1;
        const int idx = sIdx[row_local];
        union { float s[32]; float4 f[8]; } tmp;
        if (USE_ET) {
            const float4* src = (const float4*)(Et + idx * 64 + half * 32);
            #pragma unroll
            for (int q4 = 0; q4 < 8; ++q4) tmp.f[q4] = src[q4];
        } else {
            #pragma unroll
            for (int dd = 0; dd < 32; ++dd) tmp.s[dd] = E[(half * 32 + dd) * 1024 + idx];
        }
        float4* dst = (float4*)(out + (b * 128 + row_local) * 64 + half * 32);
        #pragma unroll
        for (int q4 = 0; q4 < 8; ++q4) dst[q4] = tmp.f[q4];
    }

    // loss: wave reduce -> block reduce -> one atomic; last block writes scalar
    #pragma unroll
    for (int mask = 32; mask >= 1; mask >>= 1) la += __shfl_xor(la, mask);
    if (l == 0) sRed[w] = la;
    __syncthreads();
    if (tid == 0) {
        atomicAdd(ws_loss, sRed[0] + sRed[1] + sRed[2] + sRed[3]);
        __threadfence();
        unsigned prev = atomicAdd(ws_cnt, 1u);
        if (prev == 1023u) {
            float total = atomicAdd(ws_loss, 0.f);
            out[8388608] = total * (1.25f / 8388608.f);
        }
    }
}

extern "C" void kernel_launch(void* const* d_in, const int* in_sizes, int n_in,
                              void* d_out, int out_size, void* d_ws, size_t ws_size,
                              hipStream_t stream) {
    const float* z = (const float*)d_in[0];  // fp32 [131072,64]
    const float* E = (const float*)d_in[1];  // fp32 [64,1024]
    float* out = (float*)d_out;              // fp32 [8388609]

    char* ws = (char*)d_ws;
    float* loss = (float*)ws;               // 4 B
    unsigned* cnt = (unsigned*)(ws + 64);   // 4 B
    float* enorm = (float*)(ws + 128);      // 4 KB
    float* Et = (float*)(ws + 8192);        // 256 KB (optional)
    const bool useEt = ws_size >= (size_t)(8192 + 65536 * 4);

    vq_prep<<<256, 256, 0, stream>>>(E, Et, loss, cnt, enorm, useEt ? 1 : 0);
    if (useEt)
        vq_main<true><<<1024, 256, 0, stream>>>(z, E, Et, enorm, loss, cnt, out);
    else
        vq_main<false><<<1024, 256, 0, stream>>>(z, E, Et, enorm, loss, cnt, out);
}